// Round 4
// baseline (41.576 us; speedup 1.0000x reference)
//
#include <hip/hip_runtime.h>
#include <math.h>

#define TROWS 16
#define FFEAT 129
#define DD    64

__device__ __forceinline__ float lane_bcast(float v, int k) {
    return __uint_as_float(__builtin_amdgcn_readlane(__float_as_uint(v), k));
}

// x + dpp_mov(x, ctrl); invalid source lanes contribute 0 (bound_ctrl=true).
#define DPP_ADD(x, ctrl)                                                     \
    (x) += __int_as_float(__builtin_amdgcn_update_dpp(                       \
        0, __float_as_int(x), (ctrl), 0xf, 0xf, true))

// 6-step DPP ladder; grand total lands in lane 63.
#define WAVE_LADDER(x)                                                       \
    do {                                                                     \
        DPP_ADD(x, 0x111); DPP_ADD(x, 0x112); DPP_ADD(x, 0x114);             \
        DPP_ADD(x, 0x118); DPP_ADD(x, 0x142); DPP_ADD(x, 0x143);             \
    } while (0)

__global__ __launch_bounds__(256, 4) void dtw_tracker_kernel(
    const float* __restrict__ fh,
    const float* __restrict__ W1,
    const float* __restrict__ b1,
    const float* __restrict__ gamma,
    const float* __restrict__ beta,
    const float* __restrict__ W2,
    const float* __restrict__ b2,
    float* __restrict__ out,
    int nB)
{
    const int tid  = threadIdx.x;
    const int lane = tid & 63;
    const int wib  = tid >> 6;

    // Lane holds column `lane` of W1 in 64 VGPRs (coalesced, L2-hot).
    float w1c[DD];
    #pragma unroll
    for (int k = 0; k < DD; ++k) w1c[k] = W1[k * DD + lane];

    const float b1j = b1[lane];
    const float gj  = gamma[lane];
    const float bj  = beta[lane];
    const float w2j = W2[lane];
    const float b2s = b2[0];

    const int S = gridDim.x * 4;            // total waves
    int bA = blockIdx.x * 4 + wib;          // batch for stream A
    if (bA >= nB) return;
    int bB = bA + S;                        // batch for stream B

    const size_t rowOff = 13 * FFEAT + lane;

    // Prime the pipeline: load both streams' rows.
    const float* pA = fh + (size_t)bA * (TROWS * FFEAT) + rowOff;
    const int bBl = (bB < nB) ? bB : bA;
    const float* pB = fh + (size_t)bBl * (TROWS * FFEAT) + rowOff;
    float xA13 = pA[0], xA14 = pA[FFEAT], xA15 = pA[2 * FFEAT];
    float xB13 = pB[0], xB14 = pB[FFEAT], xB15 = pB[2 * FFEAT];

    while (bA < nB) {
        const bool hasB = (bB < nB);

        // ---- prefetch next pair (overlaps all compute below) ----
        const int nA = bA + 2 * S;
        const int nBt = nA + S;
        const int nAl = (nA < nB) ? nA : bA;
        const int nBl = (nBt < nB) ? nBt : nAl;
        const float* qA = fh + (size_t)nAl * (TROWS * FFEAT) + rowOff;
        const float* qB = fh + (size_t)nBl * (TROWS * FFEAT) + rowOff;
        const float yA13 = qA[0], yA14 = qA[FFEAT], yA15 = qA[2 * FFEAT];
        const float yB13 = qB[0], yB14 = qB[FFEAT], yB15 = qB[2 * FFEAT];

        // ---- clips (both streams) ----
        const float aA13 = fminf(fmaxf(fabsf(xA13), 1e-5f), 10.0f);
        const float aA14 = fminf(fmaxf(fabsf(xA14), 1e-5f), 10.0f);
        const float aA15 = fminf(fmaxf(fabsf(xA15), 1e-5f), 10.0f);
        const float aB13 = fminf(fmaxf(fabsf(xB13), 1e-5f), 10.0f);
        const float aB14 = fminf(fmaxf(fabsf(xB14), 1e-5f), 10.0f);
        const float aB15 = fminf(fmaxf(fabsf(xB15), 1e-5f), 10.0f);

        // ---- six independent DPP ladders run together (great ILP) ----
        float sA  = aA13 + aA14 + aA15;
        float qAx = fmaf(aA13, aA13, fmaf(aA14, aA14, aA15 * aA15));
        float sB  = aB13 + aB14 + aB15;
        float qBx = fmaf(aB13, aB13, fmaf(aB14, aB14, aB15 * aB15));
        const float dA0 = xA13 - xA15;
        const float dB0 = xB13 - xB15;
        float ddA = dA0 * dA0;
        float ddB = dB0 * dB0;
        WAVE_LADDER(sA);  WAVE_LADDER(sB);
        WAVE_LADDER(qAx); WAVE_LADDER(qBx);
        WAVE_LADDER(ddA); WAVE_LADDER(ddB);
        const float SA  = lane_bcast(sA, 63),  SB  = lane_bcast(sB, 63);
        const float QA  = lane_bcast(qAx, 63), QB  = lane_bcast(qBx, 63);
        const float DDA = lane_bcast(ddA, 63), DDB = lane_bcast(ddB, 63);

        const float meanA = SA * (1.0f / 192.0f);
        const float meanB = SB * (1.0f / 192.0f);
        float varA = (QA - SA * SA * (1.0f / 192.0f)) * (1.0f / 191.0f);
        float varB = (QB - SB * SB * (1.0f / 192.0f)) * (1.0f / 191.0f);
        varA = fmaxf(varA, 0.0f);
        varB = fmaxf(varB, 0.0f);
        const float stdA = sqrtf(varA) + 1e-5f;
        const float stdB = sqrtf(varB) + 1e-5f;

        const float latA = fminf(fmaxf(__fdividef(aA15 - meanA, stdA), -3.0f), 3.0f);
        const float latB = fminf(fmaxf(__fdividef(aB15 - meanB, stdB), -3.0f), 3.0f);

        // ---- matvec, both streams interleaved (8 accumulators) ----
        float hA0 = 0.f, hA1 = 0.f, hA2 = 0.f, hA3 = 0.f;
        float hB0 = 0.f, hB1 = 0.f, hB2 = 0.f, hB3 = 0.f;
        #pragma unroll
        for (int k = 0; k < DD; k += 4) {
            hA0 = fmaf(lane_bcast(latA, k + 0), w1c[k + 0], hA0);
            hB0 = fmaf(lane_bcast(latB, k + 0), w1c[k + 0], hB0);
            hA1 = fmaf(lane_bcast(latA, k + 1), w1c[k + 1], hA1);
            hB1 = fmaf(lane_bcast(latB, k + 1), w1c[k + 1], hB1);
            hA2 = fmaf(lane_bcast(latA, k + 2), w1c[k + 2], hA2);
            hB2 = fmaf(lane_bcast(latB, k + 2), w1c[k + 2], hB2);
            hA3 = fmaf(lane_bcast(latA, k + 3), w1c[k + 3], hA3);
            hB3 = fmaf(lane_bcast(latB, k + 3), w1c[k + 3], hB3);
        }
        const float hA = b1j + ((hA0 + hA1) + (hA2 + hA3));
        const float hB = b1j + ((hB0 + hB1) + (hB2 + hB3));

        // ---- LayerNorm: 4 ladders interleaved ----
        float hsA = hA, hqA = hA * hA, hsB = hB, hqB = hB * hB;
        WAVE_LADDER(hsA); WAVE_LADDER(hsB);
        WAVE_LADDER(hqA); WAVE_LADDER(hqB);
        const float HSA = lane_bcast(hsA, 63), HSB = lane_bcast(hsB, 63);
        const float HQA = lane_bcast(hqA, 63), HQB = lane_bcast(hqB, 63);

        const float muA = HSA * (1.0f / 64.0f);
        const float muB = HSB * (1.0f / 64.0f);
        float vA = HQA * (1.0f / 64.0f) - muA * muA;
        float vB = HQB * (1.0f / 64.0f) - muB * muB;
        vA = fmaxf(vA, 0.0f);
        vB = fmaxf(vB, 0.0f);
        const float rsA = rsqrtf(vA + 1e-5f);
        const float rsB = rsqrtf(vB + 1e-5f);
        const float hnA = (hA - muA) * rsA * gj + bj;
        const float hnB = (hB - muB) * rsB * gj + bj;

        const float gA = 0.5f * hnA * (1.0f + erff(hnA * 0.70710678118654752440f));
        const float gB = 0.5f * hnB * (1.0f + erff(hnB * 0.70710678118654752440f));

        // ---- final score ladders ----
        float scA = gA * w2j, scB = gB * w2j;
        WAVE_LADDER(scA); WAVE_LADDER(scB);
        const float SCA = lane_bcast(scA, 63), SCB = lane_bcast(scB, 63);

        const float repA = __fdividef(1.0f, 1.0f + __expf(-(SCA + b2s)));
        const float simA = __expf(-sqrtf(DDA) * (1.0f / 256.0f));
        const float repB = __fdividef(1.0f, 1.0f + __expf(-(SCB + b2s)));
        const float simB = __expf(-sqrtf(DDB) * (1.0f / 256.0f));

        if (lane == 0) {
            out[bA]      = repA;
            out[nB + bA] = simA;
            if (hasB) {
                out[bB]      = repB;
                out[nB + bB] = simB;
            }
        }

        // rotate pipeline
        bA = nA; bB = nBt;
        xA13 = yA13; xA14 = yA14; xA15 = yA15;
        xB13 = yB13; xB14 = yB14; xB15 = yB15;
    }
}

extern "C" void kernel_launch(void* const* d_in, const int* in_sizes, int n_in,
                              void* d_out, int out_size, void* d_ws, size_t ws_size,
                              hipStream_t stream) {
    const float* fh    = (const float*)d_in[0];
    const float* W1    = (const float*)d_in[1];
    const float* b1    = (const float*)d_in[2];
    const float* gamma = (const float*)d_in[3];
    const float* beta  = (const float*)d_in[4];
    const float* W2    = (const float*)d_in[5];
    const float* b2    = (const float*)d_in[6];
    float* out = (float*)d_out;

    const int nB = in_sizes[0] / (TROWS * FFEAT);   // 65536

    // 1024 blocks x 4 waves = 4096 waves = exactly one resident round at
    // occupancy 4/SIMD; each wave: 16 batches = 8 iterations x 2 streams.
    dtw_tracker_kernel<<<1024, 256, 0, stream>>>(fh, W1, b1, gamma, beta, W2, b2,
                                                 out, nB);
}

// Round 5
// 39.774 us; speedup vs baseline: 1.0453x; 1.0453x over previous
//
#include <hip/hip_runtime.h>
#include <math.h>

#define TROWS 16
#define FFEAT 129
#define DD    64

__device__ __forceinline__ float lane_bcast(float v, int k) {
    return __uint_as_float(__builtin_amdgcn_readlane(__float_as_uint(v), k));
}

// x + dpp_mov(x, ctrl); invalid source lanes contribute 0 (bound_ctrl=true).
#define DPP_ADD(x, ctrl)                                                     \
    (x) += __int_as_float(__builtin_amdgcn_update_dpp(                       \
        0, __float_as_int(x), (ctrl), 0xf, 0xf, true))

// 6-step DPP ladder; grand total lands in lane 63.
#define WAVE_LADDER(x)                                                       \
    do {                                                                     \
        DPP_ADD(x, 0x111); DPP_ADD(x, 0x112); DPP_ADD(x, 0x114);             \
        DPP_ADD(x, 0x118); DPP_ADD(x, 0x142); DPP_ADD(x, 0x143);             \
    } while (0)

__global__ __launch_bounds__(256, 4) void dtw_tracker_kernel(
    const float* __restrict__ fh,
    const float* __restrict__ W1,
    const float* __restrict__ b1,
    const float* __restrict__ gamma,
    const float* __restrict__ beta,
    const float* __restrict__ W2,
    const float* __restrict__ b2,
    float* __restrict__ out,
    int nB)
{
    const int tid  = threadIdx.x;
    const int lane = tid & 63;
    const int wib  = tid >> 6;

    // Lane holds column `lane` of W1 in 64 VGPRs (coalesced, L2-hot).
    float w1c[DD];
    #pragma unroll
    for (int k = 0; k < DD; ++k) w1c[k] = W1[k * DD + lane];

    const float b1j = b1[lane];
    const float gj  = gamma[lane];
    const float bj  = beta[lane];
    const float w2j = W2[lane];
    const float b2s = b2[0];

    const int S = gridDim.x * 4;            // total waves (8192)
    int b = blockIdx.x * 4 + wib;
    if (b >= nB) return;

    const size_t rowOff = 13 * FFEAT + lane;

    // ---- depth-2 software pipeline: cur (x), +1 (p), +2 issued in-loop ----
    const float* a0 = fh + (size_t)b * (TROWS * FFEAT) + rowOff;
    float x13 = a0[0], x14 = a0[FFEAT], x15 = a0[2 * FFEAT];

    const int bp  = b + S;
    const int bpc = (bp < nB) ? bp : b;
    const float* a1 = fh + (size_t)bpc * (TROWS * FFEAT) + rowOff;
    float p13 = a1[0], p14 = a1[FFEAT], p15 = a1[2 * FFEAT];

    while (b < nB) {
        // ---- issue loads for b+2S (6 loads now in flight per wave) ----
        const int b2i = b + 2 * S;
        const int b2c = (b2i < nB) ? b2i : b;
        const float* a2 = fh + (size_t)b2c * (TROWS * FFEAT) + rowOff;
        const float q13 = a2[0], q14 = a2[FFEAT], q15 = a2[2 * FFEAT];

        // ---- hfm = clip(|x|, 1e-5, 10) ----
        const float c13 = fminf(fmaxf(fabsf(x13), 1e-5f), 10.0f);
        const float c14 = fminf(fmaxf(fabsf(x14), 1e-5f), 10.0f);
        const float c15 = fminf(fmaxf(fabsf(x15), 1e-5f), 10.0f);

        // ---- three independent DPP ladders (S, SQ, dist) ----
        float s  = c13 + c14 + c15;
        float sq = fmaf(c13, c13, fmaf(c14, c14, c15 * c15));
        const float d0 = x13 - x15;          // RAW rows for dtw distance
        float dd = d0 * d0;
        WAVE_LADDER(s); WAVE_LADDER(sq); WAVE_LADDER(dd);
        const float Ssum = lane_bcast(s, 63);
        const float SQs  = lane_bcast(sq, 63);
        const float DDs  = lane_bcast(dd, 63);

        const float mean = Ssum * (1.0f / 192.0f);
        float var = (SQs - Ssum * Ssum * (1.0f / 192.0f)) * (1.0f / 191.0f);
        var = fmaxf(var, 0.0f);
        const float stdv = sqrtf(var) + 1e-5f;
        const float latest =
            fminf(fmaxf(__fdividef(c15 - mean, stdv), -3.0f), 3.0f);

        // ---- h = latest @ W1 + b1 (readlane broadcast, 4 accumulators) ----
        float h0 = 0.f, h1 = 0.f, h2 = 0.f, h3 = 0.f;
        #pragma unroll
        for (int k = 0; k < DD; k += 4) {
            h0 = fmaf(lane_bcast(latest, k + 0), w1c[k + 0], h0);
            h1 = fmaf(lane_bcast(latest, k + 1), w1c[k + 1], h1);
            h2 = fmaf(lane_bcast(latest, k + 2), w1c[k + 2], h2);
            h3 = fmaf(lane_bcast(latest, k + 3), w1c[k + 3], h3);
        }
        const float h = b1j + ((h0 + h1) + (h2 + h3));

        // ---- LayerNorm (two interleaved ladders) ----
        float hs = h, hq = h * h;
        WAVE_LADDER(hs); WAVE_LADDER(hq);
        const float HS = lane_bcast(hs, 63);
        const float HQ = lane_bcast(hq, 63);
        const float mu = HS * (1.0f / 64.0f);
        float vh = HQ * (1.0f / 64.0f) - mu * mu;
        vh = fmaxf(vh, 0.0f);
        const float rstd = rsqrtf(vh + 1e-5f);
        const float hn = (h - mu) * rstd * gj + bj;

        // ---- GELU via tanh form (|err| in g ~1e-3, threshold 1.9e-2) ----
        const float y  = 0.7978845608028654f *
                         fmaf(0.044715f * hn * hn, hn, hn);
        const float ey = __expf(2.0f * y);
        const float th = 1.0f - __fdividef(2.0f, ey + 1.0f);
        const float g  = 0.5f * hn * (1.0f + th);

        // ---- final score ladder ----
        float sc = g * w2j;
        WAVE_LADDER(sc);
        const float SC = lane_bcast(sc, 63);

        if (lane == 0) {
            out[b]      = __fdividef(1.0f, 1.0f + __expf(-(SC + b2s)));
            out[nB + b] = __expf(-sqrtf(DDs) * (1.0f / 256.0f));
        }

        // ---- rotate pipeline ----
        b += S;
        x13 = p13; x14 = p14; x15 = p15;
        p13 = q13; p14 = q14; p15 = q15;
    }
}

extern "C" void kernel_launch(void* const* d_in, const int* in_sizes, int n_in,
                              void* d_out, int out_size, void* d_ws, size_t ws_size,
                              hipStream_t stream) {
    const float* fh    = (const float*)d_in[0];
    const float* W1    = (const float*)d_in[1];
    const float* b1    = (const float*)d_in[2];
    const float* gamma = (const float*)d_in[3];
    const float* beta  = (const float*)d_in[4];
    const float* W2    = (const float*)d_in[5];
    const float* b2    = (const float*)d_in[6];
    float* out = (float*)d_out;

    const int nB = in_sizes[0] / (TROWS * FFEAT);   // 65536

    // 2048 blocks x 4 waves = 8192 waves; 8 batches/wave, depth-2 prefetch.
    dtw_tracker_kernel<<<2048, 256, 0, stream>>>(fh, W1, b1, gamma, beta, W2, b2,
                                                 out, nB);
}

// Round 6
// 29.709 us; speedup vs baseline: 1.3994x; 1.3388x over previous
//
#include <hip/hip_runtime.h>
#include <math.h>

#define TROWS 16
#define FFEAT 129
#define DD    64
#define TILE  64          // batches per block (16 per wave)
#define LROW  72          // ushort elems per LDS latent row (64 + 8 pad = 144 B)

typedef float f32x4 __attribute__((ext_vector_type(4)));
typedef short s16x8 __attribute__((ext_vector_type(8)));

__device__ __forceinline__ float lane_bcast(float v, int k) {
    return __uint_as_float(__builtin_amdgcn_readlane(__float_as_uint(v), k));
}

// x += dpp_mov(x, ctrl); invalid lanes contribute 0 (bound_ctrl=true).
#define DPP_ADD(x, ctrl)                                                     \
    (x) += __int_as_float(__builtin_amdgcn_update_dpp(                       \
        0, __float_as_int(x), (ctrl), 0xf, 0xf, true))

// Full 64-lane sum; grand total in lane 63.
#define WAVE_LADDER(x)                                                       \
    do {                                                                     \
        DPP_ADD(x, 0x111); DPP_ADD(x, 0x112); DPP_ADD(x, 0x114);             \
        DPP_ADD(x, 0x118); DPP_ADD(x, 0x142); DPP_ADD(x, 0x143);             \
    } while (0)

// 16-lane rotate-reduce (row_ror 8,4,2,1): ALL 16 lanes of each DPP row end
// up holding the full row sum — no broadcast step needed.
#define ROW_REDUCE(x)                                                        \
    do {                                                                     \
        DPP_ADD(x, 0x128); DPP_ADD(x, 0x124);                                \
        DPP_ADD(x, 0x122); DPP_ADD(x, 0x121);                                \
    } while (0)

__device__ __forceinline__ unsigned short f32_to_bf16(float f) {
    unsigned int u = __float_as_uint(f);
    return (unsigned short)((u + 0x7fffu + ((u >> 16) & 1u)) >> 16);
}

__global__ __launch_bounds__(256, 4) void dtw_tracker_kernel(
    const float* __restrict__ fh,
    const float* __restrict__ W1,
    const float* __restrict__ b1,
    const float* __restrict__ gamma,
    const float* __restrict__ beta,
    const float* __restrict__ W2,
    const float* __restrict__ b2,
    float* __restrict__ out,
    int nB)
{
    __shared__ unsigned short sLat[TILE * LROW];   // 9216 B

    const int tid  = threadIdx.x;
    const int lane = tid & 63;
    const int wib  = tid >> 6;
    const int n0   = lane & 15;     // N-col within tile / A-row (batch)
    const int kg   = lane >> 4;     // k-group

    // ---- B fragments: W1 as bf16. elem j of group kg <-> k = s*32 + kg*8 + j.
    // A uses the SAME mapping, so any HW k-permutation cancels.
    s16x8 Bf[2][4];
    #pragma unroll
    for (int s = 0; s < 2; ++s) {
        #pragma unroll
        for (int t = 0; t < 4; ++t) {
            #pragma unroll
            for (int j = 0; j < 8; ++j) {
                const float w = W1[(s * 32 + kg * 8 + j) * DD + (n0 + 16 * t)];
                Bf[s][t][j] = (short)f32_to_bf16(w);
            }
        }
    }

    // Per-lane epilogue constants (feature n = n0 + 16t).
    float b1v[4], gv[4], bv[4], w2v[4];
    #pragma unroll
    for (int t = 0; t < 4; ++t) {
        const int nt = n0 + 16 * t;
        b1v[t] = b1[nt]; gv[t] = gamma[nt]; bv[t] = beta[nt]; w2v[t] = W2[nt];
    }
    const float b2s = b2[0];

    // =========== Phase A: stats + latest (wave = batch, 16 iterations) =====
    const int bbase = blockIdx.x * TILE;
    const int bw    = bbase + wib * 16;          // this wave's first batch
    const size_t rowOff = (size_t)13 * FFEAT + lane;

    const float* p0 = fh + (size_t)bw * (TROWS * FFEAT) + rowOff;
    float x13 = p0[0], x14 = p0[FFEAT], x15 = p0[2 * FFEAT];

    #pragma unroll 1
    for (int i = 0; i < 16; ++i) {
        // prefetch next batch (consecutive -> L2-friendly)
        const int inext = (i < 15) ? i + 1 : 15;
        const float* pn = fh + (size_t)(bw + inext) * (TROWS * FFEAT) + rowOff;
        const float y13 = pn[0], y14 = pn[FFEAT], y15 = pn[2 * FFEAT];

        const float c13 = fminf(fmaxf(fabsf(x13), 1e-5f), 10.0f);
        const float c14 = fminf(fmaxf(fabsf(x14), 1e-5f), 10.0f);
        const float c15 = fminf(fmaxf(fabsf(x15), 1e-5f), 10.0f);

        float s  = c13 + c14 + c15;
        float sq = fmaf(c13, c13, fmaf(c14, c14, c15 * c15));
        const float d0 = x13 - x15;              // RAW rows for dtw distance
        float dd = d0 * d0;
        WAVE_LADDER(s); WAVE_LADDER(sq); WAVE_LADDER(dd);
        const float Ssum = lane_bcast(s, 63);
        const float SQs  = lane_bcast(sq, 63);
        const float DDs  = lane_bcast(dd, 63);

        const float mean = Ssum * (1.0f / 192.0f);
        float var = (SQs - Ssum * Ssum * (1.0f / 192.0f)) * (1.0f / 191.0f);
        var = fmaxf(var, 0.0f);
        const float stdv = sqrtf(var) + 1e-5f;
        const float latest =
            fminf(fmaxf(__fdividef(c15 - mean, stdv), -3.0f), 3.0f);

        sLat[(wib * 16 + i) * LROW + lane] = f32_to_bf16(latest);

        if (lane == 0)
            out[nB + (bw + i)] = __expf(-sqrtf(DDs) * (1.0f / 256.0f));

        x13 = y13; x14 = y14; x15 = y15;
    }
    // No barrier: each wave reads back only the LDS rows it wrote.

    // =========== Phase B: 16x64 @ 64x64 via MFMA, then LN/GELU/W2 ==========
    const int r = wib * 16 + n0;                 // A-row = batch within tile
    const unsigned short* ar = &sLat[r * LROW + kg * 8];
    const s16x8 a0 = *(const s16x8*)(ar);        // k = kg*8+j      (s=0)
    const s16x8 a1 = *(const s16x8*)(ar + 32);   // k = 32+kg*8+j   (s=1)

    f32x4 acc[4];
    #pragma unroll
    for (int t = 0; t < 4; ++t) {
        acc[t] = f32x4{0.0f, 0.0f, 0.0f, 0.0f};
        acc[t] = __builtin_amdgcn_mfma_f32_16x16x32_bf16(a0, Bf[0][t], acc[t], 0, 0, 0);
        acc[t] = __builtin_amdgcn_mfma_f32_16x16x32_bf16(a1, Bf[1][t], acc[t], 0, 0, 0);
    }

    // D layout: batch m = kg*4 + q (within M-tile), feature n = n0 + 16t.
    #pragma unroll
    for (int q = 0; q < 4; ++q) {
        const float h0 = acc[0][q] + b1v[0];
        const float h1 = acc[1][q] + b1v[1];
        const float h2 = acc[2][q] + b1v[2];
        const float h3 = acc[3][q] + b1v[3];

        float s  = (h0 + h1) + (h2 + h3);
        float ss = fmaf(h0, h0, fmaf(h1, h1, fmaf(h2, h2, h3 * h3)));
        ROW_REDUCE(s); ROW_REDUCE(ss);           // sums over the 64 features

        const float mu = s * (1.0f / 64.0f);
        float vv = ss * (1.0f / 64.0f) - mu * mu;
        vv = fmaxf(vv, 0.0f);
        const float rstd = rsqrtf(vv + 1e-5f);

        float sc = 0.0f;
        #pragma unroll
        for (int t = 0; t < 4; ++t) {
            const float hv = (t == 0) ? h0 : (t == 1) ? h1 : (t == 2) ? h2 : h3;
            const float hn = (hv - mu) * rstd * gv[t] + bv[t];
            const float y  = 0.7978845608028654f *
                             fmaf(0.044715f * hn * hn, hn, hn);
            const float ey = __expf(2.0f * y);
            const float th = 1.0f - __fdividef(2.0f, ey + 1.0f);
            const float g  = 0.5f * hn * (1.0f + th);
            sc = fmaf(g, w2v[t], sc);
        }
        ROW_REDUCE(sc);

        const float rep = __fdividef(1.0f, 1.0f + __expf(-(sc + b2s)));
        if (n0 == q) {
            const int bidx = bbase + wib * 16 + kg * 4 + q;
            out[bidx] = rep;
        }
    }
}

extern "C" void kernel_launch(void* const* d_in, const int* in_sizes, int n_in,
                              void* d_out, int out_size, void* d_ws, size_t ws_size,
                              hipStream_t stream) {
    const float* fh    = (const float*)d_in[0];
    const float* W1    = (const float*)d_in[1];
    const float* b1    = (const float*)d_in[2];
    const float* gamma = (const float*)d_in[3];
    const float* beta  = (const float*)d_in[4];
    const float* W2    = (const float*)d_in[5];
    const float* b2    = (const float*)d_in[6];
    float* out = (float*)d_out;

    const int nB = in_sizes[0] / (TROWS * FFEAT);   // 65536

    // One 64-batch tile per block: 1024 blocks = 4/CU, single round, no tail.
    const int nBlocks = nB / TILE;
    dtw_tracker_kernel<<<nBlocks, 256, 0, stream>>>(fh, W1, b1, gamma, beta,
                                                    W2, b2, out, nB);
}

// Round 7
// 25.683 us; speedup vs baseline: 1.6188x; 1.1568x over previous
//
#include <hip/hip_runtime.h>
#include <math.h>

#define TROWS 16
#define FFEAT 129
#define DD    64
#define TILE  64          // batches per block (16 per wave)
#define LROW  72          // ushort elems per LDS latent row (144 B, 16B-divisible)

typedef float f32x4 __attribute__((ext_vector_type(4)));
typedef short s16x8 __attribute__((ext_vector_type(8)));
typedef unsigned short u16x4 __attribute__((ext_vector_type(4)));

// x += dpp_mov(x, ctrl); invalid lanes contribute 0 (bound_ctrl=true).
#define DPP_ADD(x, ctrl)                                                     \
    (x) += __int_as_float(__builtin_amdgcn_update_dpp(                       \
        0, __float_as_int(x), (ctrl), 0xf, 0xf, true))

// 16-lane rotate-reduce (row_ror 8,4,2,1): ALL 16 lanes of a DPP row end up
// holding the full row sum (verified by R6's passing phase B).
#define ROW_REDUCE(x)                                                        \
    do {                                                                     \
        DPP_ADD(x, 0x128); DPP_ADD(x, 0x124);                                \
        DPP_ADD(x, 0x122); DPP_ADD(x, 0x121);                                \
    } while (0)

__device__ __forceinline__ unsigned short f32_to_bf16(float f) {
    unsigned int u = __float_as_uint(f);
    return (unsigned short)((u + 0x7fffu + ((u >> 16) & 1u)) >> 16);
}

// k-slot permutation shared by A and B fragments: slot s <-> column
// perm(s) = (s>>2) + 16*(s&3). Dot products are k-permutation invariant.
__device__ __forceinline__ int kperm(int s) {
    return (s >> 2) + ((s & 3) << 4);
}

// Load rows 13..15, cols {ll+16c}, of batch b: 12 coalesced scalar loads.
__device__ __forceinline__ void load12(float v[12], const float* __restrict__ fh,
                                       int b, int ll) {
    const float* base = fh + (size_t)b * (TROWS * FFEAT) + 13 * FFEAT + ll;
    #pragma unroll
    for (int r = 0; r < 3; ++r)
        #pragma unroll
        for (int c = 0; c < 4; ++c)
            v[r * 4 + c] = base[r * FFEAT + 16 * c];
}

__global__ __launch_bounds__(256, 4) void dtw_tracker_kernel(
    const float* __restrict__ fh,
    const float* __restrict__ W1,
    const float* __restrict__ b1,
    const float* __restrict__ gamma,
    const float* __restrict__ beta,
    const float* __restrict__ W2,
    const float* __restrict__ b2,
    float* __restrict__ out,
    int nB)
{
    __shared__ unsigned short sLat[TILE * LROW];   // 9216 B

    const int tid  = threadIdx.x;
    const int lane = tid & 63;
    const int wib  = tid >> 6;
    const int n0   = lane & 15;     // phase A: ll (col sub-index); B: n-col / A-row
    const int kg   = lane >> 4;     // phase A: group (batch); B: k-group

    // ---- B fragments: W1 as bf16, gathered through kperm ----
    s16x8 Bf[2][4];
    #pragma unroll
    for (int h = 0; h < 2; ++h) {
        #pragma unroll
        for (int t = 0; t < 4; ++t) {
            #pragma unroll
            for (int j = 0; j < 8; ++j) {
                const int s = h * 32 + kg * 8 + j;
                const float w = W1[kperm(s) * DD + (n0 + 16 * t)];
                Bf[h][t][j] = (short)f32_to_bf16(w);
            }
        }
    }

    // Per-lane epilogue constants (feature n = n0 + 16t).
    float b1v[4], gv[4], bv[4], w2v[4];
    #pragma unroll
    for (int t = 0; t < 4; ++t) {
        const int nt = n0 + 16 * t;
        b1v[t] = b1[nt]; gv[t] = gamma[nt]; bv[t] = beta[nt]; w2v[t] = W2[nt];
    }
    const float b2s = b2[0];

    // =========== Phase A: 4 iterations, 4 batches each (16-lane groups) ====
    const int bbase = blockIdx.x * TILE;
    const int wb    = bbase + wib * 16;          // wave's first batch
    const int ll    = n0;                        // lane within group
    const int g     = kg;                        // group = batch offset

    float cur[12], nxt[12];
    load12(cur, fh, wb + g, ll);

    #pragma unroll
    for (int i = 0; i < 4; ++i) {
        if (i < 3) load12(nxt, fh, wb + 4 * (i + 1) + g, ll);

        // clipped magnitudes
        float cl[12];
        #pragma unroll
        for (int j = 0; j < 12; ++j)
            cl[j] = fminf(fmaxf(fabsf(cur[j]), 1e-5f), 10.0f);

        // per-lane partials: sum, sumsq over 12; dist over row13-row15 (RAW)
        float s = 0.0f, sq = 0.0f, dd = 0.0f;
        #pragma unroll
        for (int j = 0; j < 12; ++j) { s += cl[j]; sq = fmaf(cl[j], cl[j], sq); }
        #pragma unroll
        for (int c = 0; c < 4; ++c) {
            const float d = cur[c] - cur[8 + c];
            dd = fmaf(d, d, dd);
        }
        // three independent 4-step reduces over the 16-lane group
        ROW_REDUCE(s); ROW_REDUCE(sq); ROW_REDUCE(dd);

        const float mean = s * (1.0f / 192.0f);
        float var = (sq - s * s * (1.0f / 192.0f)) * (1.0f / 191.0f);
        var = fmaxf(var, 0.0f);
        const float stdv = sqrtf(var) + 1e-5f;
        const float rinv = __fdividef(1.0f, stdv);

        // latest cols {ll+16c} -> LDS slots ll*4+c (kperm order), one b64 write
        u16x4 pk;
        #pragma unroll
        for (int c = 0; c < 4; ++c) {
            const float lat =
                fminf(fmaxf((cl[8 + c] - mean) * rinv, -3.0f), 3.0f);
            pk[c] = f32_to_bf16(lat);
        }
        const int row = wib * 16 + 4 * i + g;
        *(u16x4*)&sLat[row * LROW + ll * 4] = pk;

        if (ll == 0)
            out[nB + (wb + 4 * i + g)] = __expf(-sqrtf(dd) * (1.0f / 256.0f));

        #pragma unroll
        for (int j = 0; j < 12; ++j) cur[j] = nxt[j];
    }
    // No barrier: each wave reads back only the LDS rows it wrote.

    // =========== Phase B: 16x64 @ 64x64 via MFMA, then LN/GELU/W2 ==========
    const int r = wib * 16 + n0;                 // A-row = batch within tile
    const unsigned short* ar = &sLat[r * LROW + kg * 8];
    const s16x8 a0 = *(const s16x8*)(ar);        // slots kg*8+j        (h=0)
    const s16x8 a1 = *(const s16x8*)(ar + 32);   // slots 32+kg*8+j     (h=1)

    f32x4 acc[4];
    #pragma unroll
    for (int t = 0; t < 4; ++t) {
        acc[t] = f32x4{0.0f, 0.0f, 0.0f, 0.0f};
        acc[t] = __builtin_amdgcn_mfma_f32_16x16x32_bf16(a0, Bf[0][t], acc[t], 0, 0, 0);
        acc[t] = __builtin_amdgcn_mfma_f32_16x16x32_bf16(a1, Bf[1][t], acc[t], 0, 0, 0);
    }

    // D layout: batch m = kg*4 + q (within M-tile), feature n = n0 + 16t.
    #pragma unroll
    for (int q = 0; q < 4; ++q) {
        const float h0 = acc[0][q] + b1v[0];
        const float h1 = acc[1][q] + b1v[1];
        const float h2 = acc[2][q] + b1v[2];
        const float h3 = acc[3][q] + b1v[3];

        float s  = (h0 + h1) + (h2 + h3);
        float ss = fmaf(h0, h0, fmaf(h1, h1, fmaf(h2, h2, h3 * h3)));
        ROW_REDUCE(s); ROW_REDUCE(ss);           // sums over the 64 features

        const float mu = s * (1.0f / 64.0f);
        float vv = ss * (1.0f / 64.0f) - mu * mu;
        vv = fmaxf(vv, 0.0f);
        const float rstd = rsqrtf(vv + 1e-5f);

        float sc = 0.0f;
        #pragma unroll
        for (int t = 0; t < 4; ++t) {
            const float hv = (t == 0) ? h0 : (t == 1) ? h1 : (t == 2) ? h2 : h3;
            const float hn = (hv - mu) * rstd * gv[t] + bv[t];
            const float y  = 0.7978845608028654f *
                             fmaf(0.044715f * hn * hn, hn, hn);
            const float ey = __expf(2.0f * y);
            const float th = 1.0f - __fdividef(2.0f, ey + 1.0f);
            const float ge = 0.5f * hn * (1.0f + th);
            sc = fmaf(ge, w2v[t], sc);
        }
        ROW_REDUCE(sc);

        const float rep = __fdividef(1.0f, 1.0f + __expf(-(sc + b2s)));
        if (n0 == q) {
            const int bidx = bbase + wib * 16 + kg * 4 + q;
            out[bidx] = rep;
        }
    }
}

extern "C" void kernel_launch(void* const* d_in, const int* in_sizes, int n_in,
                              void* d_out, int out_size, void* d_ws, size_t ws_size,
                              hipStream_t stream) {
    const float* fh    = (const float*)d_in[0];
    const float* W1    = (const float*)d_in[1];
    const float* b1    = (const float*)d_in[2];
    const float* gamma = (const float*)d_in[3];
    const float* beta  = (const float*)d_in[4];
    const float* W2    = (const float*)d_in[5];
    const float* b2    = (const float*)d_in[6];
    float* out = (float*)d_out;

    const int nB = in_sizes[0] / (TROWS * FFEAT);   // 65536

    // One 64-batch tile per block: 1024 blocks = 4/CU, single round, no tail.
    const int nBlocks = nB / TILE;
    dtw_tracker_kernel<<<nBlocks, 256, 0, stream>>>(fh, W1, b1, gamma, beta,
                                                    W2, b2, out, nB);
}